// Round 1
// baseline (970.713 us; speedup 1.0000x reference)
//
#include <hip/hip_runtime.h>
#include <math.h>

#define NN   100000
#define NE   1600000
#define DIN  128
#define DH   64
#define DOUT 40
#define BN_EPS 1e-5f

// ---------------- init: deg = 1 (self loop), stats = 0 ----------------
__global__ void k_init(float* __restrict__ deg, float* __restrict__ stats) {
  int i = blockIdx.x * blockDim.x + threadIdx.x;
  if (i < NN) deg[i] = 1.0f;
  if (i < 128) stats[i] = 0.0f;
}

// ---------------- degree accumulation over dst ----------------
__global__ void k_deg(const int* __restrict__ dst, float* __restrict__ deg) {
  int e = blockIdx.x * blockDim.x + threadIdx.x;
  if (e < NE) atomicAdd(&deg[dst[e]], 1.0f);
}

__global__ void k_dinv(float* __restrict__ deg) {
  int i = blockIdx.x * blockDim.x + threadIdx.x;
  if (i < NN) deg[i] = rsqrtf(deg[i]);
}

// ---------------- h1 = x0 @ W1   [N,128]x[128,64] ----------------
__global__ void __launch_bounds__(256) k_gemm1(const float* __restrict__ X,
                                               const float* __restrict__ W,
                                               float* __restrict__ Hout) {
  int row = blockIdx.x * blockDim.x + threadIdx.x;
  if (row >= NN) return;
  float acc[DH];
#pragma unroll
  for (int j = 0; j < DH; ++j) acc[j] = 0.0f;
  const float4* xr = (const float4*)(X + (size_t)row * DIN);
  for (int k4 = 0; k4 < DIN / 4; ++k4) {
    float4 xv = xr[k4];
#pragma unroll
    for (int kk = 0; kk < 4; ++kk) {
      float xs = (&xv.x)[kk];
      const float* wr = W + (k4 * 4 + kk) * DH;  // wave-uniform -> s_load
#pragma unroll
      for (int j = 0; j < DH; ++j) acc[j] = fmaf(xs, wr[j], acc[j]);
    }
  }
  float4* o = (float4*)(Hout + (size_t)row * DH);
#pragma unroll
  for (int j4 = 0; j4 < DH / 4; ++j4)
    o[j4] = make_float4(acc[4 * j4], acc[4 * j4 + 1], acc[4 * j4 + 2], acc[4 * j4 + 3]);
}

// ---------------- agg = h * dinv^2 + b  (self-loop + bias prefold) ----------------
__global__ void k_initagg(const float* __restrict__ H, const float* __restrict__ dinv,
                          const float* __restrict__ bias, float* __restrict__ Agg) {
  int i = blockIdx.x * blockDim.x + threadIdx.x;
  if (i >= NN * DH) return;
  int n = i >> 6, c = i & 63;
  float di = dinv[n];
  Agg[i] = H[i] * di * di + bias[c];
}

// ---------------- edge scatter: agg[dst] += h[src] * dinv[src]*dinv[dst] ----------------
__global__ void __launch_bounds__(256) k_scatter(const int* __restrict__ src,
                                                 const int* __restrict__ dst,
                                                 const float* __restrict__ dinv,
                                                 const float* __restrict__ H,
                                                 float* __restrict__ Agg) {
  int t = blockIdx.x * blockDim.x + threadIdx.x;
  int e = t >> 6;
  if (e >= NE) return;
  int c = t & 63;
  int s = src[e], d = dst[e];
  float w = dinv[s] * dinv[d];
  atomicAdd(&Agg[(size_t)d * DH + c], H[(size_t)s * DH + c] * w);
}

// ---------------- batchnorm stats: sum, sumsq per channel ----------------
__global__ void k_stats(const float* __restrict__ Agg, float* __restrict__ stats) {
  int c = threadIdx.x & 63;
  int rg = threadIdx.x >> 6;  // 0..3
  float s1 = 0.0f, s2 = 0.0f;
  for (int n = blockIdx.x * 4 + rg; n < NN; n += gridDim.x * 4) {
    float v = Agg[(size_t)n * DH + c];
    s1 += v;
    s2 += v * v;
  }
  __shared__ float red[512];
  red[threadIdx.x] = s1;
  red[256 + threadIdx.x] = s2;
  __syncthreads();
  if (rg == 0) {
    s1 = red[c] + red[64 + c] + red[128 + c] + red[192 + c];
    s2 = red[256 + c] + red[320 + c] + red[384 + c] + red[448 + c];
    atomicAdd(&stats[c], s1);
    atomicAdd(&stats[64 + c], s2);
  }
}

// ---------------- finalize BN: scale/shift ----------------
__global__ void k_bnfinal(const float* __restrict__ stats, const float* __restrict__ g,
                          const float* __restrict__ be, float* __restrict__ scsh) {
  int c = threadIdx.x;  // 64 threads
  float mean = stats[c] * (1.0f / NN);
  float var = stats[64 + c] * (1.0f / NN) - mean * mean;
  float sc = g[c] * rsqrtf(var + BN_EPS);
  scsh[c] = sc;
  scsh[64 + c] = be[c] - mean * sc;
}

// ---------------- x1 = relu(bn(agg1)) in place; h2 = x1@W2; agg2 = h2*dinv^2+b2 ----------------
__global__ void __launch_bounds__(256) k_bngemm2(float* __restrict__ Agg1,
                                                 const float* __restrict__ scsh,
                                                 const float* __restrict__ W2,
                                                 const float* __restrict__ b2,
                                                 const float* __restrict__ dinv,
                                                 float* __restrict__ H2,
                                                 float* __restrict__ Agg2) {
  int row = blockIdx.x * blockDim.x + threadIdx.x;
  if (row >= NN) return;
  float acc[DH];
#pragma unroll
  for (int j = 0; j < DH; ++j) acc[j] = 0.0f;
  float4* ar = (float4*)(Agg1 + (size_t)row * DH);
  for (int k4 = 0; k4 < DH / 4; ++k4) {
    float4 v = ar[k4];
    float x1v[4];
#pragma unroll
    for (int kk = 0; kk < 4; ++kk) {
      int k = k4 * 4 + kk;
      float t = (&v.x)[kk] * scsh[k] + scsh[64 + k];
      x1v[kk] = fmaxf(t, 0.0f);
      const float* wr = W2 + k * DH;  // wave-uniform
#pragma unroll
      for (int j = 0; j < DH; ++j) acc[j] = fmaf(x1v[kk], wr[j], acc[j]);
    }
    ar[k4] = make_float4(x1v[0], x1v[1], x1v[2], x1v[3]);  // x1 written in place
  }
  float di = dinv[row];
  di *= di;
  float4* h2o = (float4*)(H2 + (size_t)row * DH);
  float4* a2o = (float4*)(Agg2 + (size_t)row * DH);
#pragma unroll
  for (int j4 = 0; j4 < DH / 4; ++j4) {
    float4 hv = make_float4(acc[4 * j4], acc[4 * j4 + 1], acc[4 * j4 + 2], acc[4 * j4 + 3]);
    h2o[j4] = hv;
    a2o[j4] = make_float4(hv.x * di + b2[4 * j4], hv.y * di + b2[4 * j4 + 1],
                          hv.z * di + b2[4 * j4 + 2], hv.w * di + b2[4 * j4 + 3]);
  }
}

// ---------------- out = log_softmax(concat(x1,x2) @ Wl + bl) ----------------
__global__ void __launch_bounds__(256) k_final(const float* __restrict__ X1,
                                               const float* __restrict__ A2,
                                               const float* __restrict__ Wl,
                                               const float* __restrict__ bl,
                                               float* __restrict__ Out) {
  int row = blockIdx.x * blockDim.x + threadIdx.x;
  if (row >= NN) return;
  float acc[DOUT];
#pragma unroll
  for (int j = 0; j < DOUT; ++j) acc[j] = bl[j];
  const float4* xr = (const float4*)(X1 + (size_t)row * DH);
  for (int k4 = 0; k4 < DH / 4; ++k4) {
    float4 v = xr[k4];
#pragma unroll
    for (int kk = 0; kk < 4; ++kk) {
      const float* wr = Wl + (k4 * 4 + kk) * DOUT;  // wave-uniform
      float xs = (&v.x)[kk];
#pragma unroll
      for (int j = 0; j < DOUT; ++j) acc[j] = fmaf(xs, wr[j], acc[j]);
    }
  }
  const float4* yr = (const float4*)(A2 + (size_t)row * DH);
  for (int k4 = 0; k4 < DH / 4; ++k4) {
    float4 v = yr[k4];
#pragma unroll
    for (int kk = 0; kk < 4; ++kk) {
      const float* wr = Wl + (DH + k4 * 4 + kk) * DOUT;
      float xs = (&v.x)[kk];
#pragma unroll
      for (int j = 0; j < DOUT; ++j) acc[j] = fmaf(xs, wr[j], acc[j]);
    }
  }
  float m = acc[0];
#pragma unroll
  for (int j = 1; j < DOUT; ++j) m = fmaxf(m, acc[j]);
  float s = 0.0f;
#pragma unroll
  for (int j = 0; j < DOUT; ++j) s += __expf(acc[j] - m);
  float lse = m + __logf(s);
  float* o = Out + (size_t)row * DOUT;
#pragma unroll
  for (int j4 = 0; j4 < DOUT / 4; ++j4)
    ((float4*)o)[j4] = make_float4(acc[4 * j4] - lse, acc[4 * j4 + 1] - lse,
                                   acc[4 * j4 + 2] - lse, acc[4 * j4 + 3] - lse);
}

extern "C" void kernel_launch(void* const* d_in, const int* in_sizes, int n_in,
                              void* d_out, int out_size, void* d_ws, size_t ws_size,
                              hipStream_t stream) {
  const float* x0  = (const float*)d_in[0];
  const int*   ei  = (const int*)d_in[1];
  const float* W1  = (const float*)d_in[2];
  const float* b1  = (const float*)d_in[3];
  const float* g1  = (const float*)d_in[4];
  const float* be1 = (const float*)d_in[5];
  const float* W2  = (const float*)d_in[6];
  const float* b2  = (const float*)d_in[7];
  const float* Wl  = (const float*)d_in[8];
  const float* bl  = (const float*)d_in[9];
  float* out = (float*)d_out;

  const int* src = ei;
  const int* dst = ei + NE;

  float* ws    = (float*)d_ws;
  float* deg   = ws;                   // N floats (becomes dinv in place)
  float* stats = ws + 102400;          // 128 floats: sum, sumsq
  float* scsh  = stats + 128;          // 128 floats: scale, shift
  float* Hbuf  = ws + 102400 + 512;    // N*64 (h1, then reused for h2)
  float* Agg1  = Hbuf + (size_t)NN * DH;  // N*64 (agg1, then x1 in place)
  float* Agg2  = Agg1 + (size_t)NN * DH;  // N*64

  const int B = 256;
  int gN  = (NN + B - 1) / B;             // 391
  int gE  = (NE + B - 1) / B;             // 6250
  int gNC = (NN * DH + B - 1) / B;        // 25000
  int gEC = (int)(((size_t)NE * DH + B - 1) / B);  // 400000

  k_init<<<gN, B, 0, stream>>>(deg, stats);
  k_deg<<<gE, B, 0, stream>>>(dst, deg);
  k_dinv<<<gN, B, 0, stream>>>(deg);

  k_gemm1<<<gN, B, 0, stream>>>(x0, W1, Hbuf);
  k_initagg<<<gNC, B, 0, stream>>>(Hbuf, deg, b1, Agg1);
  k_scatter<<<gEC, B, 0, stream>>>(src, dst, deg, Hbuf, Agg1);

  k_stats<<<256, B, 0, stream>>>(Agg1, stats);
  k_bnfinal<<<1, 64, 0, stream>>>(stats, g1, be1, scsh);

  k_bngemm2<<<gN, B, 0, stream>>>(Agg1, scsh, W2, b2, deg, Hbuf, Agg2);
  k_scatter<<<gEC, B, 0, stream>>>(src, dst, deg, Hbuf, Agg2);

  k_final<<<gN, B, 0, stream>>>(Agg1, Agg2, Wl, bl, out);
}

// Round 2
// 686.732 us; speedup vs baseline: 1.4135x; 1.4135x over previous
//
#include <hip/hip_runtime.h>
#include <math.h>

#define NN   100000
#define NE   1600000
#define DIN  128
#define DH   64
#define DOUT 40
#define BN_EPS 1e-5f
#define NBLK 98   // ceil(NN/1024)

// ---------------- init: hist=0, cursor=0, stats=0 ----------------
__global__ void k_init(int* __restrict__ hist, int* __restrict__ cursor,
                       float* __restrict__ stats) {
  int i = blockIdx.x * blockDim.x + threadIdx.x;
  if (i < NN) { hist[i] = 0; cursor[i] = 0; }
  if (i < 128) stats[i] = 0.0f;
}

// ---------------- int histogram over dst ----------------
__global__ void k_hist(const int* __restrict__ dst, int* __restrict__ hist) {
  int e = blockIdx.x * blockDim.x + threadIdx.x;
  if (e < NE) atomicAdd(&hist[dst[e]], 1);
}

// ---------------- dinv = rsqrt(1 + deg) ----------------
__global__ void k_dinv(const int* __restrict__ hist, float* __restrict__ dinv) {
  int i = blockIdx.x * blockDim.x + threadIdx.x;
  if (i < NN) dinv[i] = rsqrtf(1.0f + (float)hist[i]);
}

// ---------------- scan A: per-1024-block exclusive scan of hist ----------------
__global__ void __launch_bounds__(1024) k_scanA(const int* __restrict__ hist,
                                                int* __restrict__ rowptr,
                                                int* __restrict__ btot) {
  __shared__ int sh[1024];
  int t = threadIdx.x, b = blockIdx.x;
  int i = b * 1024 + t;
  int v = (i < NN) ? hist[i] : 0;
  sh[t] = v;
  __syncthreads();
  for (int off = 1; off < 1024; off <<= 1) {
    int u = (t >= off) ? sh[t - off] : 0;
    __syncthreads();
    sh[t] += u;
    __syncthreads();
  }
  if (i < NN) rowptr[i] = sh[t] - v;  // exclusive
  if (t == 1023) btot[b] = sh[t];
}

// ---------------- scan B: add block offsets (tops scanned redundantly) ----------------
__global__ void __launch_bounds__(1024) k_scanB(int* __restrict__ rowptr,
                                                const int* __restrict__ btot) {
  __shared__ int sh[128];
  int t = threadIdx.x, b = blockIdx.x;
  if (t < 128) sh[t] = (t < NBLK) ? btot[t] : 0;
  __syncthreads();
  for (int off = 1; off < 128; off <<= 1) {
    int u = (t >= off && t < 128) ? sh[t - off] : 0;
    __syncthreads();
    if (t < 128) sh[t] += u;
    __syncthreads();
  }
  int i = b * 1024 + t;
  if (i < NN && b > 0) rowptr[i] += sh[b - 1];
}

// ---------------- fill CSR: csr[rowptr[d] + cursor[d]++] = src ----------------
__global__ void k_fill(const int* __restrict__ src, const int* __restrict__ dst,
                       const int* __restrict__ rowptr, int* __restrict__ cursor,
                       int* __restrict__ csr) {
  int e = blockIdx.x * blockDim.x + threadIdx.x;
  if (e >= NE) return;
  int d = dst[e];
  int pos = rowptr[d] + atomicAdd(&cursor[d], 1);
  csr[pos] = src[e];
}

// ---------------- h1 = x0 @ W1   [N,128]x[128,64] ----------------
__global__ void __launch_bounds__(256) k_gemm1(const float* __restrict__ X,
                                               const float* __restrict__ W,
                                               float* __restrict__ Hout) {
  int row = blockIdx.x * blockDim.x + threadIdx.x;
  if (row >= NN) return;
  float acc[DH];
#pragma unroll
  for (int j = 0; j < DH; ++j) acc[j] = 0.0f;
  const float4* xr = (const float4*)(X + (size_t)row * DIN);
  for (int k4 = 0; k4 < DIN / 4; ++k4) {
    float4 xv = xr[k4];
#pragma unroll
    for (int kk = 0; kk < 4; ++kk) {
      float xs = (&xv.x)[kk];
      const float* wr = W + (k4 * 4 + kk) * DH;
#pragma unroll
      for (int j = 0; j < DH; ++j) acc[j] = fmaf(xs, wr[j], acc[j]);
    }
  }
  float4* o = (float4*)(Hout + (size_t)row * DH);
#pragma unroll
  for (int j4 = 0; j4 < DH / 4; ++j4)
    o[j4] = make_float4(acc[4 * j4], acc[4 * j4 + 1], acc[4 * j4 + 2], acc[4 * j4 + 3]);
}

// ---------------- pull-gather: Agg[d] = H[d]*dinv[d]^2 + b + sum_in H[s]*dinv[s]*dinv[d] ----------------
__global__ void __launch_bounds__(256) k_gather(const int* __restrict__ csr,
                                                const int* __restrict__ rowptr,
                                                const int* __restrict__ cnt,
                                                const float* __restrict__ dinv,
                                                const float* __restrict__ H,
                                                const float* __restrict__ bias,
                                                float* __restrict__ Agg) {
  int d = (blockIdx.x * 256 + threadIdx.x) >> 6;  // one wave per node; grid exact
  int c = threadIdx.x & 63;
  float wd = dinv[d];
  float acc = H[(size_t)d * DH + c] * wd * wd + bias[c];
  int st = rowptr[d], n = cnt[d];
  for (int k = 0; k < n; ++k) {
    int s = csr[st + k];
    acc = fmaf(H[(size_t)s * DH + c], dinv[s] * wd, acc);
  }
  Agg[(size_t)d * DH + c] = acc;
}

// ---------------- batchnorm stats: sum, sumsq per channel ----------------
__global__ void k_stats(const float* __restrict__ Agg, float* __restrict__ stats) {
  int c = threadIdx.x & 63;
  int rg = threadIdx.x >> 6;  // 0..3
  float s1 = 0.0f, s2 = 0.0f;
  for (int n = blockIdx.x * 4 + rg; n < NN; n += gridDim.x * 4) {
    float v = Agg[(size_t)n * DH + c];
    s1 += v;
    s2 += v * v;
  }
  __shared__ float red[512];
  red[threadIdx.x] = s1;
  red[256 + threadIdx.x] = s2;
  __syncthreads();
  if (rg == 0) {
    s1 = red[c] + red[64 + c] + red[128 + c] + red[192 + c];
    s2 = red[256 + c] + red[320 + c] + red[384 + c] + red[448 + c];
    atomicAdd(&stats[c], s1);
    atomicAdd(&stats[64 + c], s2);
  }
}

// ---------------- finalize BN: scale/shift ----------------
__global__ void k_bnfinal(const float* __restrict__ stats, const float* __restrict__ g,
                          const float* __restrict__ be, float* __restrict__ scsh) {
  int c = threadIdx.x;  // 64 threads
  float mean = stats[c] * (1.0f / NN);
  float var = stats[64 + c] * (1.0f / NN) - mean * mean;
  float sc = g[c] * rsqrtf(var + BN_EPS);
  scsh[c] = sc;
  scsh[64 + c] = be[c] - mean * sc;
}

// ---------------- x1 = relu(bn(agg1)) in place; h2 = x1@W2 ----------------
__global__ void __launch_bounds__(256) k_bngemm2(float* __restrict__ Agg1,
                                                 const float* __restrict__ scsh,
                                                 const float* __restrict__ W2,
                                                 float* __restrict__ H2) {
  int row = blockIdx.x * blockDim.x + threadIdx.x;
  if (row >= NN) return;
  float acc[DH];
#pragma unroll
  for (int j = 0; j < DH; ++j) acc[j] = 0.0f;
  float4* ar = (float4*)(Agg1 + (size_t)row * DH);
  for (int k4 = 0; k4 < DH / 4; ++k4) {
    float4 v = ar[k4];
    float x1v[4];
#pragma unroll
    for (int kk = 0; kk < 4; ++kk) {
      int k = k4 * 4 + kk;
      float t = (&v.x)[kk] * scsh[k] + scsh[64 + k];
      x1v[kk] = fmaxf(t, 0.0f);
      const float* wr = W2 + k * DH;
#pragma unroll
      for (int j = 0; j < DH; ++j) acc[j] = fmaf(x1v[kk], wr[j], acc[j]);
    }
    ar[k4] = make_float4(x1v[0], x1v[1], x1v[2], x1v[3]);  // x1 in place
  }
  float4* h2o = (float4*)(H2 + (size_t)row * DH);
#pragma unroll
  for (int j4 = 0; j4 < DH / 4; ++j4)
    h2o[j4] = make_float4(acc[4 * j4], acc[4 * j4 + 1], acc[4 * j4 + 2], acc[4 * j4 + 3]);
}

// ---------------- fused gather2 + concat GEMM + log_softmax ----------------
__global__ void __launch_bounds__(256) k_g2final(const int* __restrict__ csr,
                                                 const int* __restrict__ rowptr,
                                                 const int* __restrict__ cnt,
                                                 const float* __restrict__ dinv,
                                                 const float* __restrict__ H2,
                                                 const float* __restrict__ b2,
                                                 const float* __restrict__ X1,
                                                 const float* __restrict__ Wl,
                                                 const float* __restrict__ bl,
                                                 float* __restrict__ Out) {
  __shared__ float lx[4][64];
  __shared__ float la[4][64];
  int w = threadIdx.x >> 6, c = threadIdx.x & 63;
  int d = blockIdx.x * 4 + w;  // grid exact: 25000*4 = NN
  float wd = dinv[d];
  float acc = H2[(size_t)d * DH + c] * wd * wd + b2[c];
  lx[w][c] = X1[(size_t)d * DH + c];
  int st = rowptr[d], n = cnt[d];
  for (int k = 0; k < n; ++k) {
    int s = csr[st + k];
    acc = fmaf(H2[(size_t)s * DH + c], dinv[s] * wd, acc);
  }
  la[w][c] = acc;
  // same-wave LDS write->read: compiler inserts lgkmcnt wait; no block barrier needed
  float o = -1e30f;
  if (c < DOUT) {
    o = bl[c];
#pragma unroll 8
    for (int k = 0; k < DH; ++k) o = fmaf(lx[w][k], Wl[k * DOUT + c], o);
#pragma unroll 8
    for (int k = 0; k < DH; ++k) o = fmaf(la[w][k], Wl[(DH + k) * DOUT + c], o);
  }
  float m = o;
#pragma unroll
  for (int msk = 1; msk < 64; msk <<= 1) m = fmaxf(m, __shfl_xor(m, msk));
  float ee = (c < DOUT) ? __expf(o - m) : 0.0f;
  float ssum = ee;
#pragma unroll
  for (int msk = 1; msk < 64; msk <<= 1) ssum += __shfl_xor(ssum, msk);
  float lse = m + __logf(ssum);
  if (c < DOUT) Out[(size_t)d * DOUT + c] = o - lse;
}

extern "C" void kernel_launch(void* const* d_in, const int* in_sizes, int n_in,
                              void* d_out, int out_size, void* d_ws, size_t ws_size,
                              hipStream_t stream) {
  const float* x0  = (const float*)d_in[0];
  const int*   ei  = (const int*)d_in[1];
  const float* W1  = (const float*)d_in[2];
  const float* b1  = (const float*)d_in[3];
  const float* g1  = (const float*)d_in[4];
  const float* be1 = (const float*)d_in[5];
  const float* W2  = (const float*)d_in[6];
  const float* b2  = (const float*)d_in[7];
  const float* Wl  = (const float*)d_in[8];
  const float* bl  = (const float*)d_in[9];
  float* out = (float*)d_out;

  const int* src = ei;
  const int* dst = ei + NE;

  // workspace layout (floats/ints, 4B each)
  char* w8 = (char*)d_ws;
  int*   hist   = (int*)w8;                       // NN
  int*   cursor = hist + NN;                      // NN
  int*   rowptr = cursor + NN;                    // NN (+pad)
  int*   btot   = rowptr + NN + 64;               // 128
  float* stats  = (float*)(btot + 128);           // 128
  float* scsh   = stats + 128;                    // 128
  float* dinv   = scsh + 128;                     // NN
  int*   csr    = (int*)(dinv + NN + 64);         // NE
  float* Hbuf   = (float*)(csr + NE + 64);        // NN*64 (h1 then h2)
  float* Agg1   = Hbuf + (size_t)NN * DH;         // NN*64 (agg1 then x1)

  const int B = 256;
  int gN = (NN + B - 1) / B;   // 391
  int gE = (NE + B - 1) / B;   // 6250
  int gW = NN / 4;             // 25000, exact

  k_init<<<gN, B, 0, stream>>>(hist, cursor, stats);
  k_hist<<<gE, B, 0, stream>>>(dst, hist);
  k_dinv<<<gN, B, 0, stream>>>(hist, dinv);
  k_scanA<<<NBLK, 1024, 0, stream>>>(hist, rowptr, btot);
  k_scanB<<<NBLK, 1024, 0, stream>>>(rowptr, btot);
  k_fill<<<gE, B, 0, stream>>>(src, dst, rowptr, cursor, csr);

  k_gemm1<<<gN, B, 0, stream>>>(x0, W1, Hbuf);
  k_gather<<<gW, B, 0, stream>>>(csr, rowptr, hist, dinv, Hbuf, b1, Agg1);

  k_stats<<<256, B, 0, stream>>>(Agg1, stats);
  k_bnfinal<<<1, 64, 0, stream>>>(stats, g1, be1, scsh);

  k_bngemm2<<<gN, B, 0, stream>>>(Agg1, scsh, W2, Hbuf);
  k_g2final<<<gW, B, 0, stream>>>(csr, rowptr, hist, dinv, Hbuf, b2, Agg1, Wl, bl, out);
}

// Round 3
// 514.615 us; speedup vs baseline: 1.8863x; 1.3345x over previous
//
#include <hip/hip_runtime.h>
#include <math.h>

#define NN   100000
#define NE   1600000
#define DIN  128
#define DH   64
#define DOUT 40
#define BN_EPS 1e-5f
#define NBLK 98   // ceil(NN/1024)

typedef unsigned short ushort_t;
typedef unsigned int uint_t;

__device__ __forceinline__ float bf2f(ushort_t v) {
  union { uint_t u; float f; } w;
  w.u = ((uint_t)v) << 16;
  return w.f;
}
__device__ __forceinline__ ushort_t f2bf(float f) {  // RNE
  union { float f; uint_t u; } w;
  w.f = f;
  uint_t u = w.u;
  u += 0x7fffu + ((u >> 16) & 1u);
  return (ushort_t)(u >> 16);
}

// ---------------- init: hist=0, cursor=0, stats=0 ----------------
__global__ void k_init(int* __restrict__ hist, int* __restrict__ cursor,
                       float* __restrict__ stats) {
  int i = blockIdx.x * blockDim.x + threadIdx.x;
  if (i < NN) { hist[i] = 0; cursor[i] = 0; }
  if (i < 128) stats[i] = 0.0f;
}

// ---------------- int histogram over dst ----------------
__global__ void k_hist(const int* __restrict__ dst, int* __restrict__ hist) {
  int e = blockIdx.x * blockDim.x + threadIdx.x;
  if (e < NE) atomicAdd(&hist[dst[e]], 1);
}

// ---------------- dinv = rsqrt(1 + deg) ----------------
__global__ void k_dinv(const int* __restrict__ hist, float* __restrict__ dinv) {
  int i = blockIdx.x * blockDim.x + threadIdx.x;
  if (i < NN) dinv[i] = rsqrtf(1.0f + (float)hist[i]);
}

// ---------------- scan A: per-1024-block exclusive scan ----------------
__global__ void __launch_bounds__(1024) k_scanA(const int* __restrict__ hist,
                                                int* __restrict__ rowptr,
                                                int* __restrict__ btot) {
  __shared__ int sh[1024];
  int t = threadIdx.x, b = blockIdx.x;
  int i = b * 1024 + t;
  int v = (i < NN) ? hist[i] : 0;
  sh[t] = v;
  __syncthreads();
  for (int off = 1; off < 1024; off <<= 1) {
    int u = (t >= off) ? sh[t - off] : 0;
    __syncthreads();
    sh[t] += u;
    __syncthreads();
  }
  if (i < NN) rowptr[i] = sh[t] - v;
  if (t == 1023) btot[b] = sh[t];
}

// ---------------- scan B: add block offsets ----------------
__global__ void __launch_bounds__(1024) k_scanB(int* __restrict__ rowptr,
                                                const int* __restrict__ btot) {
  __shared__ int sh[128];
  int t = threadIdx.x, b = blockIdx.x;
  if (t < 128) sh[t] = (t < NBLK) ? btot[t] : 0;
  __syncthreads();
  for (int off = 1; off < 128; off <<= 1) {
    int u = (t >= off && t < 128) ? sh[t - off] : 0;
    __syncthreads();
    if (t < 128) sh[t] += u;
    __syncthreads();
  }
  int i = b * 1024 + t;
  if (i < NN && b > 0) rowptr[i] += sh[b - 1];
}

// ---------------- fill CSR ----------------
__global__ void k_fill(const int* __restrict__ src, const int* __restrict__ dst,
                       const int* __restrict__ rowptr, int* __restrict__ cursor,
                       int* __restrict__ csr) {
  int e = blockIdx.x * blockDim.x + threadIdx.x;
  if (e >= NE) return;
  int d = dst[e];
  int pos = rowptr[d] + atomicAdd(&cursor[d], 1);
  csr[pos] = src[e];
}

// ---------------- h1pre = (x0 @ W1) * dinv, stored bf16 ----------------
__global__ void __launch_bounds__(256) k_gemm1(const float* __restrict__ X,
                                               const float* __restrict__ W,
                                               const float* __restrict__ dinv,
                                               ushort_t* __restrict__ Hb) {
  int row = blockIdx.x * blockDim.x + threadIdx.x;
  if (row >= NN) return;
  float acc[DH];
#pragma unroll
  for (int j = 0; j < DH; ++j) acc[j] = 0.0f;
  const float4* xr = (const float4*)(X + (size_t)row * DIN);
  for (int k4 = 0; k4 < DIN / 4; ++k4) {
    float4 xv = xr[k4];
#pragma unroll
    for (int kk = 0; kk < 4; ++kk) {
      float xs = (&xv.x)[kk];
      const float* wr = W + (k4 * 4 + kk) * DH;  // wave-uniform -> s_load
#pragma unroll
      for (int j = 0; j < DH; ++j) acc[j] = fmaf(xs, wr[j], acc[j]);
    }
  }
  float di = dinv[row];
  uint_t pk[DH / 2];
#pragma unroll
  for (int j = 0; j < DH / 2; ++j)
    pk[j] = (uint_t)f2bf(acc[2 * j] * di) | ((uint_t)f2bf(acc[2 * j + 1] * di) << 16);
  uint4* o = (uint4*)(Hb + (size_t)row * DH);
#pragma unroll
  for (int q = 0; q < DH / 8; ++q)
    o[q] = make_uint4(pk[4 * q], pk[4 * q + 1], pk[4 * q + 2], pk[4 * q + 3]);
}

// ---------------- gather1 + fused BN stats ----------------
// Agg[d] = dinv[d]*(Hpre[d] + sum_in Hpre[s]) + b1;  stats += (v, v^2)
__global__ void __launch_bounds__(256) k_gather1(const int* __restrict__ csr,
                                                 const int* __restrict__ rowptr,
                                                 const int* __restrict__ cnt,
                                                 const float* __restrict__ dinv,
                                                 const ushort_t* __restrict__ Hb,
                                                 const float* __restrict__ bias,
                                                 float* __restrict__ Agg,
                                                 float* __restrict__ stats) {
  int wid = (blockIdx.x * 256 + threadIdx.x) >> 6;
  int nw = gridDim.x * 4;
  int c = threadIdx.x & 63;
  float bc = bias[c];
  float s1 = 0.0f, s2 = 0.0f;
  for (int d = wid; d < NN; d += nw) {
    int st = __builtin_amdgcn_readfirstlane(rowptr[d]);
    int n  = __builtin_amdgcn_readfirstlane(cnt[d]);
    float wd = dinv[d];
    float acc = bf2f(Hb[(size_t)d * DH + c]);  // self term (pre-scaled)
    const int* cs = csr + st;
    int k = 0;
    for (; k + 4 <= n; k += 4) {
      int i0 = cs[k], i1 = cs[k + 1], i2 = cs[k + 2], i3 = cs[k + 3];
      ushort_t u0 = Hb[(size_t)i0 * DH + c];
      ushort_t u1 = Hb[(size_t)i1 * DH + c];
      ushort_t u2 = Hb[(size_t)i2 * DH + c];
      ushort_t u3 = Hb[(size_t)i3 * DH + c];
      acc += bf2f(u0) + bf2f(u1) + bf2f(u2) + bf2f(u3);
    }
    for (; k < n; ++k) acc += bf2f(Hb[(size_t)cs[k] * DH + c]);
    float v = fmaf(acc, wd, bc);
    Agg[(size_t)d * DH + c] = v;
    s1 += v;
    s2 += v * v;
  }
  __shared__ float red[512];
  red[threadIdx.x] = s1;
  red[256 + threadIdx.x] = s2;
  __syncthreads();
  if (threadIdx.x < 64) {
    float a = red[c] + red[64 + c] + red[128 + c] + red[192 + c];
    float b = red[256 + c] + red[320 + c] + red[384 + c] + red[448 + c];
    atomicAdd(&stats[c], a);
    atomicAdd(&stats[64 + c], b);
  }
}

// ---------------- finalize BN: scale/shift ----------------
__global__ void k_bnfinal(const float* __restrict__ stats, const float* __restrict__ g,
                          const float* __restrict__ be, float* __restrict__ scsh) {
  int c = threadIdx.x;  // 64 threads
  float mean = stats[c] * (1.0f / NN);
  float var = stats[64 + c] * (1.0f / NN) - mean * mean;
  float sc = g[c] * rsqrtf(var + BN_EPS);
  scsh[c] = sc;
  scsh[64 + c] = be[c] - mean * sc;
}

// ---------------- x1 = relu(bn(agg1)) in place; h2pre = (x1@W2)*dinv bf16 ----------------
__global__ void __launch_bounds__(256) k_bngemm2(float* __restrict__ Agg1,
                                                 const float* __restrict__ scsh,
                                                 const float* __restrict__ W2,
                                                 const float* __restrict__ dinv,
                                                 ushort_t* __restrict__ Hb) {
  int row = blockIdx.x * blockDim.x + threadIdx.x;
  if (row >= NN) return;
  float acc[DH];
#pragma unroll
  for (int j = 0; j < DH; ++j) acc[j] = 0.0f;
  float4* ar = (float4*)(Agg1 + (size_t)row * DH);
  for (int k4 = 0; k4 < DH / 4; ++k4) {
    float4 v = ar[k4];
    float x1v[4];
#pragma unroll
    for (int kk = 0; kk < 4; ++kk) {
      int k = k4 * 4 + kk;
      float t = (&v.x)[kk] * scsh[k] + scsh[64 + k];
      x1v[kk] = fmaxf(t, 0.0f);
      const float* wr = W2 + k * DH;  // wave-uniform
#pragma unroll
      for (int j = 0; j < DH; ++j) acc[j] = fmaf(x1v[kk], wr[j], acc[j]);
    }
    ar[k4] = make_float4(x1v[0], x1v[1], x1v[2], x1v[3]);  // x1 in place
  }
  float di = dinv[row];
  uint_t pk[DH / 2];
#pragma unroll
  for (int j = 0; j < DH / 2; ++j)
    pk[j] = (uint_t)f2bf(acc[2 * j] * di) | ((uint_t)f2bf(acc[2 * j + 1] * di) << 16);
  uint4* o = (uint4*)(Hb + (size_t)row * DH);
#pragma unroll
  for (int q = 0; q < DH / 8; ++q)
    o[q] = make_uint4(pk[4 * q], pk[4 * q + 1], pk[4 * q + 2], pk[4 * q + 3]);
}

// ---------------- fused gather2 + concat GEMM + log_softmax ----------------
__global__ void __launch_bounds__(256) k_g2final(const int* __restrict__ csr,
                                                 const int* __restrict__ rowptr,
                                                 const int* __restrict__ cnt,
                                                 const float* __restrict__ dinv,
                                                 const ushort_t* __restrict__ Hb,
                                                 const float* __restrict__ b2,
                                                 const float* __restrict__ X1,
                                                 const float* __restrict__ Wl,
                                                 const float* __restrict__ bl,
                                                 float* __restrict__ Out) {
  __shared__ float lx[4][64];
  __shared__ float la[4][64];
  int w = threadIdx.x >> 6, c = threadIdx.x & 63;
  int d = blockIdx.x * 4 + w;  // grid exact: 25000*4 = NN
  int st = __builtin_amdgcn_readfirstlane(rowptr[d]);
  int n  = __builtin_amdgcn_readfirstlane(cnt[d]);
  float wd = dinv[d];
  float acc = bf2f(Hb[(size_t)d * DH + c]);
  lx[w][c] = X1[(size_t)d * DH + c];
  const int* cs = csr + st;
  int k = 0;
  for (; k + 4 <= n; k += 4) {
    int i0 = cs[k], i1 = cs[k + 1], i2 = cs[k + 2], i3 = cs[k + 3];
    ushort_t u0 = Hb[(size_t)i0 * DH + c];
    ushort_t u1 = Hb[(size_t)i1 * DH + c];
    ushort_t u2 = Hb[(size_t)i2 * DH + c];
    ushort_t u3 = Hb[(size_t)i3 * DH + c];
    acc += bf2f(u0) + bf2f(u1) + bf2f(u2) + bf2f(u3);
  }
  for (; k < n; ++k) acc += bf2f(Hb[(size_t)cs[k] * DH + c]);
  la[w][c] = fmaf(acc, wd, b2[c]);
  // same-wave LDS write->read: lgkmcnt ordering, no block barrier needed
  float o = -1e30f;
  if (c < DOUT) {
    o = bl[c];
#pragma unroll 8
    for (int k2 = 0; k2 < DH; ++k2) o = fmaf(lx[w][k2], Wl[k2 * DOUT + c], o);
#pragma unroll 8
    for (int k2 = 0; k2 < DH; ++k2) o = fmaf(la[w][k2], Wl[(DH + k2) * DOUT + c], o);
  }
  float m = o;
#pragma unroll
  for (int msk = 1; msk < 64; msk <<= 1) m = fmaxf(m, __shfl_xor(m, msk));
  float ee = (c < DOUT) ? __expf(o - m) : 0.0f;
  float ssum = ee;
#pragma unroll
  for (int msk = 1; msk < 64; msk <<= 1) ssum += __shfl_xor(ssum, msk);
  float lse = m + __logf(ssum);
  if (c < DOUT) Out[(size_t)d * DOUT + c] = o - lse;
}

extern "C" void kernel_launch(void* const* d_in, const int* in_sizes, int n_in,
                              void* d_out, int out_size, void* d_ws, size_t ws_size,
                              hipStream_t stream) {
  const float* x0  = (const float*)d_in[0];
  const int*   ei  = (const int*)d_in[1];
  const float* W1  = (const float*)d_in[2];
  const float* b1  = (const float*)d_in[3];
  const float* g1  = (const float*)d_in[4];
  const float* be1 = (const float*)d_in[5];
  const float* W2  = (const float*)d_in[6];
  const float* b2  = (const float*)d_in[7];
  const float* Wl  = (const float*)d_in[8];
  const float* bl  = (const float*)d_in[9];
  float* out = (float*)d_out;

  const int* src = ei;
  const int* dst = ei + NE;

  // workspace layout (all 4B-aligned; 16B alignment preserved at each buffer)
  char* w8 = (char*)d_ws;
  int*   hist   = (int*)w8;                       // NN
  int*   cursor = hist + NN;                      // NN
  int*   rowptr = cursor + NN;                    // NN (+64 pad)
  int*   btot   = rowptr + NN + 64;               // 128
  float* stats  = (float*)(btot + 128);           // 128
  float* scsh   = stats + 128;                    // 128
  float* dinv   = scsh + 128;                     // NN (+64 pad)
  int*   csr    = (int*)(dinv + NN + 64);         // NE (+64 pad)
  ushort_t* Hb  = (ushort_t*)(csr + NE + 64);     // NN*64 bf16 (h1pre then h2pre)
  float* Agg1   = (float*)(Hb + (size_t)NN * DH); // NN*64 f32 (agg1 then x1)

  const int B = 256;
  int gN = (NN + B - 1) / B;   // 391
  int gE = (NE + B - 1) / B;   // 6250
  int gW = NN / 4;             // 25000, exact

  k_init<<<gN, B, 0, stream>>>(hist, cursor, stats);
  k_hist<<<gE, B, 0, stream>>>(dst, hist);
  k_dinv<<<gN, B, 0, stream>>>(hist, dinv);
  k_scanA<<<NBLK, 1024, 0, stream>>>(hist, rowptr, btot);
  k_scanB<<<NBLK, 1024, 0, stream>>>(rowptr, btot);
  k_fill<<<gE, B, 0, stream>>>(src, dst, rowptr, cursor, csr);

  k_gemm1<<<gN, B, 0, stream>>>(x0, W1, dinv, Hb);
  k_gather1<<<2048, B, 0, stream>>>(csr, rowptr, hist, dinv, Hb, b1, Agg1, stats);
  k_bnfinal<<<1, 64, 0, stream>>>(stats, g1, be1, scsh);

  k_bngemm2<<<gN, B, 0, stream>>>(Agg1, scsh, W2, dinv, Hb);
  k_g2final<<<gW, B, 0, stream>>>(csr, rowptr, hist, dinv, Hb, b2, Agg1, Wl, bl, out);
}